// Round 7
// baseline (132.057 us; speedup 1.0000x reference)
//
#include <hip/hip_runtime.h>
#include <math.h>

#define BATCH 8
#define CH    64
#define HH    128
#define WW    128
#define HWSZ  (HH * WW)       // 16384
#define COUT  64
#define KTAPS 9
#define KDIM  576             // CH * KTAPS
#define TROWS 6               // window rows: y-2 .. y+3
#define TCOLS 36              // window cols: x0-2 .. x0+33
#define TSLOTS 216            // 6 * 36
#define WSEGU 1736            // ushorts per ch-segment (216*8=1728, +8 pad:
                              // 868 dw ≡ 4 mod 32 -> 8 segs on 8 bank phases)

typedef __attribute__((ext_vector_type(8))) short short8;
typedef __attribute__((ext_vector_type(4))) float f32x4;
typedef __attribute__((ext_vector_type(2))) float f32x2;

__device__ __forceinline__ unsigned short f2bf(float f) {
    unsigned int u = __float_as_uint(f);
    u += 0x7fffu + ((u >> 16) & 1u);
    return (unsigned short)(u >> 16);
}
__device__ __forceinline__ float bf2f(unsigned short u) {
    return __uint_as_float((unsigned int)u << 16);
}
// One-instruction packed fp32->bf16 (RNE), lo in [15:0], hi in [31:16].
__device__ __forceinline__ unsigned int cvt_pk_bf16(float lo, float hi) {
    unsigned int r;
    asm("v_cvt_pk_bf16_f32 %0, %1, %2" : "=v"(r) : "v"(lo), "v"(hi));
    return r;
}
__device__ __forceinline__ f32x2 up2(unsigned int u) {
    f32x2 r;
    r.x = __uint_as_float(u << 16);
    r.y = __uint_as_float(u & 0xffff0000u);
    return r;
}
__device__ __forceinline__ unsigned int bilin2(unsigned int a, unsigned int b,
                                               unsigned int c, unsigned int d,
                                               float w00, float w01, float w10, float w11) {
    f32x2 acc = up2(a) * w00;
    acc = up2(b) * w01 + acc;
    acc = up2(c) * w10 + acc;
    acc = up2(d) * w11 + acc;
    return cvt_pk_bf16(acc.x, acc.y);
}
// 8-channel global gather+pack (rare fallback path)
__device__ __forceinline__ uint4 ld8g(const float* p) {
    uint4 q;
    q.x = cvt_pk_bf16(p[0],        p[HWSZ]);
    q.y = cvt_pk_bf16(p[2 * HWSZ], p[3 * HWSZ]);
    q.z = cvt_pk_bf16(p[4 * HWSZ], p[5 * HWSZ]);
    q.w = cvt_pk_bf16(p[6 * HWSZ], p[7 * HWSZ]);
    return q;
}

// ---------------------------------------------------------------------------
// Kernel 0: repack conv weights into wave-contiguous A-fragment layouts.
//  wpk [mt<4][ks<18][lane<64][8]: lane(n16,quad) holds
//      w_dcn[co=mt*16+n16][c=(ks&1)*32+quad*8+j], tap=ks>>1
//  wopk[cot<2][ks<18][lane<64][8]: same for w_off (co>=27 zeroed)
// ---------------------------------------------------------------------------
__global__ __launch_bounds__(256) void prep_w_kernel(
    const float* __restrict__ w_dcn, const float* __restrict__ w_off,
    unsigned short* __restrict__ wpk, unsigned short* __restrict__ wopk) {
    int j = blockIdx.x * 256 + threadIdx.x;
    if (j < 36864) {
        int jj = j & 7, ln = (j >> 3) & 63, q = j >> 9;   // q: 0..71
        int ks = q % 18, mt = q / 18;
        int tap = ks >> 1, h = ks & 1;
        int co = mt * 16 + (ln & 15);
        int c  = h * 32 + (ln >> 4) * 8 + jj;
        wpk[j] = f2bf(w_dcn[(co * CH + c) * KTAPS + tap]);
    } else if (j < 55296) {
        int jo = j - 36864;
        int jj = jo & 7, ln = (jo >> 3) & 63, q = jo >> 9; // q: 0..35
        int ks = q % 18, cot = q / 18;
        int tap = ks >> 1, h = ks & 1;
        int co = cot * 16 + (ln & 15);
        int c  = h * 32 + (ln >> 4) * 8 + jj;
        wopk[jo] = (co < 27) ? f2bf(w_off[(co * CH + c) * KTAPS + tap]) : 0;
    }
}

// ---------------------------------------------------------------------------
// Per-tap pipeline state: bilinear weights + index + SPECULATIVELY-ISSUED
// h=0 corner reads (branchless, from clamped slot rds). All named scalar
// fields -> nothing can be runtime-indexed into scratch (R3/rule-20 lesson).
// ---------------------------------------------------------------------------
struct TapS {
    float w00, w01, w10, w11;
    unsigned int iu;      // window slot, or bit31 | packed clamped coords
    unsigned int rds;     // slot actually used for speculative reads
    uint4 a0, b0, c0, d0; // h=0 corners (segment = quad)
};

__device__ __forceinline__ TapS make_tap(int k, const unsigned short* omr16, int pl,
                                         float fybase, float fxbase, int y, int x0,
                                         const unsigned short* win, int quad) {
    TapS t;
    int ky = k / 3, kx = k - ky * 3;           // static under full unroll
    float fy = bf2f(omr16[k * 64 + pl]) + fybase + (float)ky;
    float fx = bf2f(omr16[(9 + k) * 64 + pl]) + fxbase + (float)kx;
    float m = 1.f / (1.f + __expf(-bf2f(omr16[(18 + k) * 64 + pl])));
    float y0f = floorf(fy), x0f = floorf(fx);
    float dy = fy - y0f, dx = fx - x0f;
    int y0 = (int)y0f, x0i = (int)x0f;
    int y1 = y0 + 1, x1 = x0i + 1;
    bool vy0 = (y0 >= 0) & (y0 < HH);
    bool vy1 = (y1 >= 0) & (y1 < HH);
    bool vx0 = (x0i >= 0) & (x0i < WW);
    bool vx1 = (x1 >= 0) & (x1 < WW);
    t.w00 = (1.f - dy) * (1.f - dx) * m; if (!(vy0 && vx0)) t.w00 = 0.f;
    t.w01 = (1.f - dy) * dx * m;         if (!(vy0 && vx1)) t.w01 = 0.f;
    t.w10 = dy * (1.f - dx) * m;         if (!(vy1 && vx0)) t.w10 = 0.f;
    t.w11 = dy * dx * m;                 if (!(vy1 && vx1)) t.w11 = 0.f;
    int yc0 = min(max(y0, 0), HH - 1), yc1 = min(max(y1, 0), HH - 1);
    int xc0 = min(max(x0i, 0), WW - 1), xc1 = min(max(x1, 0), WW - 1);
    int uy = y0 - (y - 2), ux = x0i - (x0 - 2);
    bool inw = ((unsigned)uy <= 4u) & ((unsigned)ux <= 34u);
    unsigned int iu;
    if (inw) iu = (unsigned)(uy * TCOLS + ux);
    else     iu = 0x80000000u | ((unsigned)yc0 << 21) | ((unsigned)xc0 << 14)
                              | ((unsigned)yc1 << 7)  | (unsigned)xc1;
    t.iu = iu;
    t.rds = (iu >> 31) ? 0u : iu;
    // speculative, BRANCHLESS h=0 corner reads -> issue-able one tap early
    const unsigned short* s0 = win + quad * WSEGU + t.rds * 8;
    t.a0 = *(const uint4*)(s0);
    t.b0 = *(const uint4*)(s0 + 8);
    t.c0 = *(const uint4*)(s0 + TCOLS * 8);
    t.d0 = *(const uint4*)(s0 + TCOLS * 8 + 8);
    return t;
}

// ---------------------------------------------------------------------------
// Kernel 1: SINGLE FUSED DCN. Block tile = 2 rows x 32 cols (64 px).
//  Stage: win[c8][216][8ch] bf16 from NCHW fp32 (zero-pad OOB, cvt_pk pack).
//  Phase 1: offset GEMM 32co x 64px; results -> omr16 bf16.
//  Phase 3: SOFTWARE-PIPELINED tap loop. make_tap(k+1) (params + branchless
//           speculative corner reads) issues BEFORE tap k's bilin/MFMA, so
//           ds_read latency hides under compute. R5/R6 showed the compiler
//           won't do this itself (VGPR stayed 48: control-dependent reads).
// LDS: win 27776 | omr16 3456 = 31232 B.
// launch_bounds(256,4): VGPR cap 128 (pipeline needs ~110); 4 blocks/CU.
// ---------------------------------------------------------------------------
__global__ __launch_bounds__(256, 4) void dcn_fused_mfma(
    const float* __restrict__ x, const unsigned short* __restrict__ wpk,
    const unsigned short* __restrict__ wopk, const float* __restrict__ b_off,
    const float* __restrict__ b_dcn, float* __restrict__ out) {
    __shared__ __align__(16) unsigned char smem[31232];
    unsigned short* win = (unsigned short*)smem;             // [8][WSEGU]
    unsigned short* omr16 = (unsigned short*)(smem + 27776); // [27][64] bf16

    int tid = threadIdx.x, bid = blockIdx.x;
    int b = bid & 7;                 // batch -> XCD pinning
    int T = bid >> 3;                // tile 0..255 per image
    int y = (T >> 2) * 2;            // tile row base (2 rows)
    int x0 = (T & 3) * 32;           // tile col base
    int lane = tid & 63, wv = tid >> 6;
    int quad = lane >> 4, n16 = lane & 15;

    const float* xbf = x + (size_t)b * CH * HWSZ;

    // ---------------- Stage window from NCHW fp32 ----------------
    for (int p = tid; p < 8 * TSLOTS; p += 256) {
        int c8 = p / TSLOTS, slot = p - c8 * TSLOTS;
        int wy = slot / TCOLS, wx = slot - wy * TCOLS;
        int iy = y - 2 + wy, ix = x0 - 2 + wx;
        bool v = (iy >= 0) & (iy < HH) & (ix >= 0) & (ix < WW);
        uint4 q = {0, 0, 0, 0};
        if (v) {
            const float* pc0 = xbf + (size_t)(c8 * 8) * HWSZ + iy * WW + ix;
            q = ld8g(pc0);
        }
        *(uint4*)&win[c8 * WSEGU + slot * 8] = q;
    }
    __syncthreads();

    // ---------------- Phase 1: offset GEMM (B from window) ----------------
    {
        int coh = wv & 1;
        int pxh = (wv >> 1) * 32;
        int prw = wv >> 1;               // this wave's px row within tile
        f32x4 oacc[2] = {{0, 0, 0, 0}, {0, 0, 0, 0}};
        for (int k = 0; k < KTAPS; ++k) {
            int ky = k / 3, kx = k - ky * 3;
#pragma unroll
            for (int h = 0; h < 2; ++h) {
                short8 afrag = *(const short8*)(wopk + (size_t)((coh * 18 + k * 2 + h) * 64 + lane) * 8);
                const unsigned short* seg = win + (h * 4 + quad) * WSEGU;
#pragma unroll
                for (int pt = 0; pt < 2; ++pt) {
                    int pc = pt * 16 + n16;
                    int slot = (prw + ky + 1) * TCOLS + pc + kx + 1;
                    short8 bfrag = *(const short8*)(seg + slot * 8);
                    oacc[pt] = __builtin_amdgcn_mfma_f32_16x16x32_bf16(afrag, bfrag,
                                                                       oacc[pt], 0, 0, 0);
                }
            }
        }
#pragma unroll
        for (int pt = 0; pt < 2; ++pt) {
#pragma unroll
            for (int r = 0; r < 4; ++r) {
                int co = coh * 16 + quad * 4 + r;
                if (co < 27)
                    omr16[co * 64 + pxh + pt * 16 + n16] = f2bf(oacc[pt][r] + b_off[co]);
            }
        }
    }
    __syncthreads();

    // ---------------- Phase 3: pipelined main GEMM ----------------
    // Wave wv owns px = wv*16 + n16 (all 64 co). Lane (quad,n16) builds the
    // MFMA B-fragment (channels h*32+quad*8+j of its px) in registers.
    f32x4 acc[4] = {{0, 0, 0, 0}, {0, 0, 0, 0}, {0, 0, 0, 0}, {0, 0, 0, 0}};
    int pl = wv * 16 + n16;
    int ho = y + (pl >> 5), wo = x0 + (pl & 31);
    float fybase = (float)(ho - 1), fxbase = (float)(wo - 1);

    TapS cur = make_tap(0, omr16, pl, fybase, fxbase, y, x0, win, quad);

#pragma unroll
    for (int k = 0; k < KTAPS; ++k) {
        // -- stage next tap: params + speculative h=0 corner reads (in
        //    flight while we compute THIS tap below)
        TapS nxt;
        if (k + 1 < KTAPS)
            nxt = make_tap(k + 1, omr16, pl, fybase, fxbase, y, x0, win, quad);

        // -- issue h=1 corner reads for CUR now (cover under fallback
        //    check + bilin h0)
        const unsigned short* s1 = win + (quad + 4) * WSEGU + cur.rds * 8;
        uint4 e0 = *(const uint4*)(s1);
        uint4 e1 = *(const uint4*)(s1 + 8);
        uint4 e2 = *(const uint4*)(s1 + TCOLS * 8);
        uint4 e3 = *(const uint4*)(s1 + TCOLS * 8 + 8);

        // -- rare fallback: overwrite speculative data with clamped global
        if (__builtin_expect((int)(cur.iu >> 31), 0)) {
            int zy0 = (int)((cur.iu >> 21) & 0x7f), zx0 = (int)((cur.iu >> 14) & 0x7f);
            int zy1 = (int)((cur.iu >> 7) & 0x7f),  zx1 = (int)(cur.iu & 0x7f);
            const float* g0 = xbf + (size_t)(quad * 8) * HWSZ;
            const float* g1 = xbf + (size_t)((quad + 4) * 8) * HWSZ;
            cur.a0 = ld8g(g0 + zy0 * WW + zx0); cur.b0 = ld8g(g0 + zy0 * WW + zx1);
            cur.c0 = ld8g(g0 + zy1 * WW + zx0); cur.d0 = ld8g(g0 + zy1 * WW + zx1);
            e0 = ld8g(g1 + zy0 * WW + zx0); e1 = ld8g(g1 + zy0 * WW + zx1);
            e2 = ld8g(g1 + zy1 * WW + zx0); e3 = ld8g(g1 + zy1 * WW + zx1);
        }

        // -- h = 0: bilin + 4 MFMA
        {
            union { uint4 u; short8 s; } cv;
            cv.u.x = bilin2(cur.a0.x, cur.b0.x, cur.c0.x, cur.d0.x,
                            cur.w00, cur.w01, cur.w10, cur.w11);
            cv.u.y = bilin2(cur.a0.y, cur.b0.y, cur.c0.y, cur.d0.y,
                            cur.w00, cur.w01, cur.w10, cur.w11);
            cv.u.z = bilin2(cur.a0.z, cur.b0.z, cur.c0.z, cur.d0.z,
                            cur.w00, cur.w01, cur.w10, cur.w11);
            cv.u.w = bilin2(cur.a0.w, cur.b0.w, cur.c0.w, cur.d0.w,
                            cur.w00, cur.w01, cur.w10, cur.w11);
            short8 bfrag = cv.s;
#pragma unroll
            for (int mt = 0; mt < 4; ++mt) {
                short8 af = *(const short8*)(wpk + (size_t)((mt * 18 + k * 2 + 0) * 64 + lane) * 8);
                acc[mt] = __builtin_amdgcn_mfma_f32_16x16x32_bf16(af, bfrag,
                                                                  acc[mt], 0, 0, 0);
            }
        }
        // -- h = 1: bilin + 4 MFMA
        {
            union { uint4 u; short8 s; } cv;
            cv.u.x = bilin2(e0.x, e1.x, e2.x, e3.x, cur.w00, cur.w01, cur.w10, cur.w11);
            cv.u.y = bilin2(e0.y, e1.y, e2.y, e3.y, cur.w00, cur.w01, cur.w10, cur.w11);
            cv.u.z = bilin2(e0.z, e1.z, e2.z, e3.z, cur.w00, cur.w01, cur.w10, cur.w11);
            cv.u.w = bilin2(e0.w, e1.w, e2.w, e3.w, cur.w00, cur.w01, cur.w10, cur.w11);
            short8 bfrag = cv.s;
#pragma unroll
            for (int mt = 0; mt < 4; ++mt) {
                short8 af = *(const short8*)(wpk + (size_t)((mt * 18 + k * 2 + 1) * 64 + lane) * 8);
                acc[mt] = __builtin_amdgcn_mfma_f32_16x16x32_bf16(af, bfrag,
                                                                  acc[mt], 0, 0, 0);
            }
        }

        if (k + 1 < KTAPS) cur = nxt;   // renamed away under full unroll
    }

    // Epilogue: D[m=quad*4+r][n=n16]; co = mt*16 + m; px = wv*16 + n16
    float* ob = out + (size_t)b * COUT * HWSZ;
    int gidx = (y + (pl >> 5)) * WW + x0 + (pl & 31);
#pragma unroll
    for (int mt = 0; mt < 4; ++mt) {
#pragma unroll
        for (int r = 0; r < 4; ++r) {
            int co = mt * 16 + quad * 4 + r;
            ob[(size_t)co * HWSZ + gidx] = acc[mt][r] + b_dcn[co];
        }
    }
}

// ---------------------------------------------------------------------------
extern "C" void kernel_launch(void* const* d_in, const int* in_sizes, int n_in,
                              void* d_out, int out_size, void* d_ws, size_t ws_size,
                              hipStream_t stream) {
    const float* x     = (const float*)d_in[0];
    const float* w_off = (const float*)d_in[1];
    const float* b_off = (const float*)d_in[2];
    const float* w_dcn = (const float*)d_in[3];
    const float* b_dcn = (const float*)d_in[4];
    float* out = (float*)d_out;

    // ws layout: wpk | wopk (bf16 repacked weights only)
    unsigned short* wpk  = (unsigned short*)d_ws;            // 36864
    unsigned short* wopk = wpk + 36864;                      // 18432

    hipLaunchKernelGGL(prep_w_kernel, dim3(216), dim3(256), 0, stream,
                       w_dcn, w_off, wpk, wopk);
    hipLaunchKernelGGL(dcn_fused_mfma, dim3(BATCH * HWSZ / 64), dim3(256),
                       0, stream, x, wpk, wopk, b_off, b_dcn, out);
}

// Round 8
// 127.596 us; speedup vs baseline: 1.0350x; 1.0350x over previous
//
#include <hip/hip_runtime.h>
#include <math.h>

#define BATCH 8
#define CH    64
#define HH    128
#define WW    128
#define HWSZ  (HH * WW)       // 16384
#define COUT  64
#define KTAPS 9
#define TROWS 8               // window rows: y-2 .. y+5 (4-row tile)
#define TCOLS 36              // window cols: x0-2 .. x0+33
#define TSLOTS 288            // 8 * 36
#define WSEGU 2312            // ushorts per ch-segment (288*8=2304, +8 pad:
                              // 1156 dw ≡ 4 mod 32 -> 8 segs on 8 bank phases)

typedef __attribute__((ext_vector_type(8)))  short short8;
typedef __attribute__((ext_vector_type(4)))  float f32x4;
typedef __attribute__((ext_vector_type(2)))  float f32x2;
typedef __attribute__((ext_vector_type(16))) float f32x16;

__device__ __forceinline__ unsigned short f2bf(float f) {
    unsigned int u = __float_as_uint(f);
    u += 0x7fffu + ((u >> 16) & 1u);
    return (unsigned short)(u >> 16);
}
__device__ __forceinline__ float bf2f(unsigned short u) {
    return __uint_as_float((unsigned int)u << 16);
}
// One-instruction packed fp32->bf16 (RNE), lo in [15:0], hi in [31:16].
__device__ __forceinline__ unsigned int cvt_pk_bf16(float lo, float hi) {
    unsigned int r;
    asm("v_cvt_pk_bf16_f32 %0, %1, %2" : "=v"(r) : "v"(lo), "v"(hi));
    return r;
}
__device__ __forceinline__ f32x2 up2(unsigned int u) {
    f32x2 r;
    r.x = __uint_as_float(u << 16);
    r.y = __uint_as_float(u & 0xffff0000u);
    return r;
}
__device__ __forceinline__ unsigned int bilin2(unsigned int a, unsigned int b,
                                               unsigned int c, unsigned int d,
                                               float w00, float w01, float w10, float w11) {
    f32x2 acc = up2(a) * w00;
    acc = up2(b) * w01 + acc;
    acc = up2(c) * w10 + acc;
    acc = up2(d) * w11 + acc;
    return cvt_pk_bf16(acc.x, acc.y);
}
// 8-channel global gather+pack (rare fallback path)
__device__ __forceinline__ uint4 ld8g(const float* p) {
    uint4 q;
    q.x = cvt_pk_bf16(p[0],        p[HWSZ]);
    q.y = cvt_pk_bf16(p[2 * HWSZ], p[3 * HWSZ]);
    q.z = cvt_pk_bf16(p[4 * HWSZ], p[5 * HWSZ]);
    q.w = cvt_pk_bf16(p[6 * HWSZ], p[7 * HWSZ]);
    return q;
}

// ---------------------------------------------------------------------------
// Kernel 0: repack conv weights.
//  wpk2 [cot<2][t<9][s<4][lane<64][8]: for mfma_32x32x16 A-operand:
//      lane l holds w_dcn[co = cot*32 + (l&31)][c = s*16 + (l>>5)*8 + j], tap t
//  wopk [cot<2][ks<18][lane<64][8]: 16x16x32 layout for offset conv
//      lane(n16,quad) holds w_off[co=cot*16+n16][c=(ks&1)*32+quad*8+j], tap=ks>>1
// ---------------------------------------------------------------------------
__global__ __launch_bounds__(256) void prep_w_kernel(
    const float* __restrict__ w_dcn, const float* __restrict__ w_off,
    unsigned short* __restrict__ wpk2, unsigned short* __restrict__ wopk) {
    int j = blockIdx.x * 256 + threadIdx.x;
    if (j < 36864) {
        int jj = j & 7, ln = (j >> 3) & 63, q = j >> 9;   // q: 0..71
        int s = q & 3, t = (q >> 2) % 9, cot = q / 36;
        int co = cot * 32 + (ln & 31);
        int c  = s * 16 + (ln >> 5) * 8 + jj;
        wpk2[j] = f2bf(w_dcn[(co * CH + c) * KTAPS + t]);
    } else if (j < 55296) {
        int jo = j - 36864;
        int jj = jo & 7, ln = (jo >> 3) & 63, q = jo >> 9; // q: 0..35
        int ks = q % 18, cot = q / 18;
        int tap = ks >> 1, h = ks & 1;
        int co = cot * 16 + (ln & 15);
        int c  = h * 32 + (ln >> 4) * 8 + jj;
        wopk[jo] = (co < 27) ? f2bf(w_off[(co * CH + c) * KTAPS + tap]) : 0;
    }
}

// ---------------------------------------------------------------------------
// Kernel 1: SINGLE FUSED DCN. Block tile = 4 rows x 32 cols (128 px), 4 waves.
//  Stage: win[c8][288 slots][8ch] bf16 <- 8x36 neighborhood (zero-pad OOB).
//  Phase 1: offset GEMM 27co x 128px (16x16x32, wopk); -> omr16 bf16 [27][128].
//  Phase 3: wave wv owns px = wv*32 + (lane&31), ALL 64 co, via
//           mfma_f32_32x32x16_bf16. Per tap: params (x2-redundant only),
//           4 K-steps of 16ch; lane (h5,n32) builds its B-frag (8 ch =
//           segment 2s+h5) from 4 window corners; 2 A-frags (co-halves).
//           B exclusive per px (no duplication); A per px halved; MFMA
//           cyc/px -18%; params/px -50%; staging redundancy 3.4x -> 2.25x.
// LDS: win 36992 | omr16 6912 = 43904 B -> 3 blocks/CU (12 waves).
// ---------------------------------------------------------------------------
__global__ __launch_bounds__(256, 3) void dcn_fused_mfma(
    const float* __restrict__ x, const unsigned short* __restrict__ wpk2,
    const unsigned short* __restrict__ wopk, const float* __restrict__ b_off,
    const float* __restrict__ b_dcn, float* __restrict__ out) {
    __shared__ __align__(16) unsigned char smem[43904];
    unsigned short* win = (unsigned short*)smem;             // [8][WSEGU]
    unsigned short* omr16 = (unsigned short*)(smem + 36992); // [27][128] bf16

    int tid = threadIdx.x, bid = blockIdx.x;
    int b = bid & 7;                 // batch -> XCD pinning
    int T = bid >> 3;                // tile 0..127 per image
    int y = (T >> 2) * 4;            // tile row base (4 rows)
    int x0 = (T & 3) * 32;           // tile col base
    int lane = tid & 63, wv = tid >> 6;
    int quad = lane >> 4, n16 = lane & 15;
    int n32 = lane & 31, h5 = lane >> 5;

    const float* xbf = x + (size_t)b * CH * HWSZ;

    // ---------------- Stage window from NCHW fp32 ----------------
    for (int p = tid; p < 8 * TSLOTS; p += 256) {     // 9 iters
        int c8 = p / TSLOTS, slot = p - c8 * TSLOTS;
        int wy = slot / TCOLS, wx = slot - wy * TCOLS;
        int iy = y - 2 + wy, ix = x0 - 2 + wx;
        bool v = (iy >= 0) & (iy < HH) & (ix >= 0) & (ix < WW);
        uint4 q = {0, 0, 0, 0};
        if (v) q = ld8g(xbf + (size_t)(c8 * 8) * HWSZ + iy * WW + ix);
        *(uint4*)&win[c8 * WSEGU + slot * 8] = q;
    }
    __syncthreads();

    // ---------------- Phase 1: offset GEMM (16x16x32, B from window) ------
    {
        int coh = wv & 1;
        int pxh = (wv >> 1) * 64;        // this wave's 64-px half
        f32x4 oacc[4] = {{0, 0, 0, 0}, {0, 0, 0, 0}, {0, 0, 0, 0}, {0, 0, 0, 0}};
        for (int k = 0; k < KTAPS; ++k) {
            int ky = k / 3, kx = k - ky * 3;
#pragma unroll
            for (int h = 0; h < 2; ++h) {
                short8 afrag = *(const short8*)(wopk + (size_t)((coh * 18 + k * 2 + h) * 64 + lane) * 8);
                const unsigned short* seg = win + (h * 4 + quad) * WSEGU;
#pragma unroll
                for (int pt = 0; pt < 4; ++pt) {
                    int pxp = pxh + pt * 16 + n16;
                    int prw = pxp >> 5, pcc = pxp & 31;
                    int slot = (prw + ky + 1) * TCOLS + pcc + kx + 1;
                    short8 bfrag = *(const short8*)(seg + slot * 8);
                    oacc[pt] = __builtin_amdgcn_mfma_f32_16x16x32_bf16(afrag, bfrag,
                                                                       oacc[pt], 0, 0, 0);
                }
            }
        }
#pragma unroll
        for (int pt = 0; pt < 4; ++pt) {
#pragma unroll
            for (int r = 0; r < 4; ++r) {
                int co = coh * 16 + quad * 4 + r;
                if (co < 27)
                    omr16[co * 128 + pxh + pt * 16 + n16] = f2bf(oacc[pt][r] + b_off[co]);
            }
        }
    }
    __syncthreads();

    // ---------------- Phase 3: main GEMM (32x32x16), params fused ---------
    f32x16 acc[2] = {{0, 0, 0, 0, 0, 0, 0, 0, 0, 0, 0, 0, 0, 0, 0, 0},
                     {0, 0, 0, 0, 0, 0, 0, 0, 0, 0, 0, 0, 0, 0, 0, 0}};
    int pl = wv * 32 + n32;                 // this lane's px (x2 over h5)
    int ho = y + (pl >> 5), wo = x0 + (pl & 31);
    float fybase = (float)(ho - 1), fxbase = (float)(wo - 1);

#pragma unroll 3
    for (int t = 0; t < KTAPS; ++t) {
        int ky = t / 3, kx = t - ky * 3;
        // ---- bilinear params for (tap t, px pl), register-only ----
        float fy = bf2f(omr16[t * 128 + pl]) + fybase + (float)ky;
        float fx = bf2f(omr16[(9 + t) * 128 + pl]) + fxbase + (float)kx;
        float m = 1.f / (1.f + __expf(-bf2f(omr16[(18 + t) * 128 + pl])));
        float y0f = floorf(fy), x0f = floorf(fx);
        float dy = fy - y0f, dx = fx - x0f;
        int y0 = (int)y0f, x0i = (int)x0f;
        int y1 = y0 + 1, x1 = x0i + 1;
        bool vy0 = (y0 >= 0) & (y0 < HH);
        bool vy1 = (y1 >= 0) & (y1 < HH);
        bool vx0 = (x0i >= 0) & (x0i < WW);
        bool vx1 = (x1 >= 0) & (x1 < WW);
        float w00 = (1.f - dy) * (1.f - dx) * m; if (!(vy0 && vx0)) w00 = 0.f;
        float w01 = (1.f - dy) * dx * m;         if (!(vy0 && vx1)) w01 = 0.f;
        float w10 = dy * (1.f - dx) * m;         if (!(vy1 && vx0)) w10 = 0.f;
        float w11 = dy * dx * m;                 if (!(vy1 && vx1)) w11 = 0.f;
        int yc0 = min(max(y0, 0), HH - 1), yc1 = min(max(y1, 0), HH - 1);
        int xc0 = min(max(x0i, 0), WW - 1), xc1 = min(max(x1, 0), WW - 1);
        int uy = y0 - (y - 2), ux = x0i - (x0 - 2);
        bool inw = ((unsigned)uy <= 6u) & ((unsigned)ux <= 34u);
        unsigned int iu;
        if (inw) iu = (unsigned)(uy * TCOLS + ux);
        else     iu = 0x80000000u | ((unsigned)yc0 << 21) | ((unsigned)xc0 << 14)
                                  | ((unsigned)yc1 << 7)  | (unsigned)xc1;

        // ---- 4 K-steps of 16 ch; lane's 8 ch = segment 2s+h5 ----
#pragma unroll
        for (int s = 0; s < 4; ++s) {
            int g = 2 * s + h5;
            uint4 qa, qb, qc, qd;
            if (__builtin_expect(!(iu & 0x80000000u), 1)) {
                const unsigned short* base = win + g * WSEGU + iu * 8;
                qa = *(const uint4*)(base);
                qb = *(const uint4*)(base + 8);
                qc = *(const uint4*)(base + TCOLS * 8);
                qd = *(const uint4*)(base + TCOLS * 8 + 8);
            } else {
                int zy0 = (int)((iu >> 21) & 0x7f), zx0 = (int)((iu >> 14) & 0x7f);
                int zy1 = (int)((iu >> 7) & 0x7f),  zx1 = (int)(iu & 0x7f);
                const float* pc0 = xbf + (size_t)(g * 8) * HWSZ;
                qa = ld8g(pc0 + zy0 * WW + zx0); qb = ld8g(pc0 + zy0 * WW + zx1);
                qc = ld8g(pc0 + zy1 * WW + zx0); qd = ld8g(pc0 + zy1 * WW + zx1);
            }
            union { uint4 u; short8 sh; } cv;
            cv.u.x = bilin2(qa.x, qb.x, qc.x, qd.x, w00, w01, w10, w11);
            cv.u.y = bilin2(qa.y, qb.y, qc.y, qd.y, w00, w01, w10, w11);
            cv.u.z = bilin2(qa.z, qb.z, qc.z, qd.z, w00, w01, w10, w11);
            cv.u.w = bilin2(qa.w, qb.w, qc.w, qd.w, w00, w01, w10, w11);
            short8 bfrag = cv.sh;

            short8 af0 = *(const short8*)(wpk2 + (size_t)(((0 * 9 + t) * 4 + s) * 64 + lane) * 8);
            acc[0] = __builtin_amdgcn_mfma_f32_32x32x16_bf16(af0, bfrag, acc[0], 0, 0, 0);
            short8 af1 = *(const short8*)(wpk2 + (size_t)(((1 * 9 + t) * 4 + s) * 64 + lane) * 8);
            acc[1] = __builtin_amdgcn_mfma_f32_32x32x16_bf16(af1, bfrag, acc[1], 0, 0, 0);
        }
    }

    // Epilogue: 32x32 C/D: col(px) = lane&31; row = (r&3)+8*(r>>2)+4*h5
    float* ob = out + (size_t)b * COUT * HWSZ;
    int gidx = (y + (pl >> 5)) * WW + x0 + (pl & 31);
#pragma unroll
    for (int cot = 0; cot < 2; ++cot) {
#pragma unroll
        for (int r = 0; r < 16; ++r) {
            int co = cot * 32 + (r & 3) + 8 * (r >> 2) + 4 * h5;
            ob[(size_t)co * HWSZ + gidx] = acc[cot][r] + b_dcn[co];
        }
    }
}

// ---------------------------------------------------------------------------
extern "C" void kernel_launch(void* const* d_in, const int* in_sizes, int n_in,
                              void* d_out, int out_size, void* d_ws, size_t ws_size,
                              hipStream_t stream) {
    const float* x     = (const float*)d_in[0];
    const float* w_off = (const float*)d_in[1];
    const float* b_off = (const float*)d_in[2];
    const float* w_dcn = (const float*)d_in[3];
    const float* b_dcn = (const float*)d_in[4];
    float* out = (float*)d_out;

    // ws layout: wpk2 | wopk (bf16 repacked weights only)
    unsigned short* wpk2 = (unsigned short*)d_ws;            // 36864
    unsigned short* wopk = wpk2 + 36864;                     // 18432

    hipLaunchKernelGGL(prep_w_kernel, dim3(216), dim3(256), 0, stream,
                       w_dcn, w_off, wpk2, wopk);
    hipLaunchKernelGGL(dcn_fused_mfma, dim3(BATCH * HWSZ / 128), dim3(256),
                       0, stream, x, wpk2, wopk, b_off, b_dcn, out);
}

// Round 10
// 122.336 us; speedup vs baseline: 1.0795x; 1.0430x over previous
//
#include <hip/hip_runtime.h>
#include <math.h>

#define BATCH 8
#define CH    64
#define HH    128
#define WW    128
#define HWSZ  (HH * WW)       // 16384
#define COUT  64
#define KTAPS 9
#define TROWS 12              // window rows: y-2 .. y+9 (8-row tile)
#define TCOLS 36              // window cols: x0-2 .. x0+33
#define TSLOTS 432            // 12 * 36
#define WSEGU 3464            // ushorts per ch-segment (432*8=3456, +8 pad:
                              // 1732 dw ≡ 4 mod 32 -> 8 segs on 8 bank phases)
#define NBLK  (BATCH * HWSZ / 256)   // 512 main-kernel blocks

typedef __attribute__((ext_vector_type(8)))  short short8;
typedef __attribute__((ext_vector_type(4)))  float f32x4;
typedef __attribute__((ext_vector_type(2)))  float f32x2;
typedef __attribute__((ext_vector_type(16))) float f32x16;

__device__ __forceinline__ unsigned short f2bf(float f) {
    unsigned int u = __float_as_uint(f);
    u += 0x7fffu + ((u >> 16) & 1u);
    return (unsigned short)(u >> 16);
}
__device__ __forceinline__ float bf2f(unsigned short u) {
    return __uint_as_float((unsigned int)u << 16);
}
// One-instruction packed fp32->bf16 (RNE), lo in [15:0], hi in [31:16].
__device__ __forceinline__ unsigned int cvt_pk_bf16(float lo, float hi) {
    unsigned int r;
    asm("v_cvt_pk_bf16_f32 %0, %1, %2" : "=v"(r) : "v"(lo), "v"(hi));
    return r;
}
__device__ __forceinline__ f32x2 up2(unsigned int u) {
    f32x2 r;
    r.x = __uint_as_float(u << 16);
    r.y = __uint_as_float(u & 0xffff0000u);
    return r;
}
__device__ __forceinline__ unsigned int bilin2(unsigned int a, unsigned int b,
                                               unsigned int c, unsigned int d,
                                               float w00, float w01, float w10, float w11) {
    f32x2 acc = up2(a) * w00;
    acc = up2(b) * w01 + acc;
    acc = up2(c) * w10 + acc;
    acc = up2(d) * w11 + acc;
    return cvt_pk_bf16(acc.x, acc.y);
}
// 8-channel global gather+pack (rare fallback path)
__device__ __forceinline__ uint4 ld8g(const float* p) {
    uint4 q;
    q.x = cvt_pk_bf16(p[0],        p[HWSZ]);
    q.y = cvt_pk_bf16(p[2 * HWSZ], p[3 * HWSZ]);
    q.z = cvt_pk_bf16(p[4 * HWSZ], p[5 * HWSZ]);
    q.w = cvt_pk_bf16(p[6 * HWSZ], p[7 * HWSZ]);
    return q;
}

// ---------------------------------------------------------------------------
// Kernel 0: repack conv weights (unchanged from R8).
//  wpk2 [cot<2][t<9][s<4][lane<64][8]: for mfma_32x32x16 A-operand:
//      lane l holds w_dcn[co = cot*32 + (l&31)][c = s*16 + (l>>5)*8 + j], tap t
//  wopk [cot<2][ks<18][lane<64][8]: 16x16x32 layout for offset conv
// ---------------------------------------------------------------------------
__global__ __launch_bounds__(256) void prep_w_kernel(
    const float* __restrict__ w_dcn, const float* __restrict__ w_off,
    unsigned short* __restrict__ wpk2, unsigned short* __restrict__ wopk) {
    int j = blockIdx.x * 256 + threadIdx.x;
    if (j < 36864) {
        int jj = j & 7, ln = (j >> 3) & 63, q = j >> 9;   // q: 0..71
        int s = q & 3, t = (q >> 2) % 9, cot = q / 36;
        int co = cot * 32 + (ln & 31);
        int c  = s * 16 + (ln >> 5) * 8 + jj;
        wpk2[j] = f2bf(w_dcn[(co * CH + c) * KTAPS + t]);
    } else if (j < 55296) {
        int jo = j - 36864;
        int jj = jo & 7, ln = (jo >> 3) & 63, q = jo >> 9; // q: 0..35
        int ks = q % 18, cot = q / 18;
        int tap = ks >> 1, h = ks & 1;
        int co = cot * 16 + (ln & 15);
        int c  = h * 32 + (ln >> 4) * 8 + jj;
        wopk[jo] = (co < 27) ? f2bf(w_off[(co * CH + c) * KTAPS + tap]) : 0;
    }
}

// ---------------------------------------------------------------------------
// Kernel 1: SINGLE FUSED DCN. Block = 512 threads (8 waves),
//           tile = 8 rows x 32 cols (256 px).
//  R9 lesson: ws-omr (global RAW across __syncthreads) returned stale/poison
//  -> NaN. Keep EVERYTHING in LDS; kill R8's residency tail by geometry:
//  grid = 512 blocks, 2 blocks/CU resident => FULLY co-resident, zero tail
//  (R8: 1024 blocks, 3 of 4 resident -> 23% occupancy, serial 4th round).
//  Stage: win[c8][432 slots][8ch] bf16 <- 12x36 neighborhood (zero-pad OOB);
//         redundancy 2.25x -> 1.69x.
//  Phase 1: offset GEMM 27co x 256px (16x16x32, wopk); wave (coh=wv&1,
//           pxh=(wv>>1)*64); -> omr bf16 [27][256] in LDS.
//  Phase 3: wave wv owns px = wv*32+n32 (all 64 co) via mfma_32x32x16.
// LDS: win 55424 | omr 13824 = 69248 B -> 2 blocks/CU (16 waves).
// ---------------------------------------------------------------------------
__global__ __launch_bounds__(512, 4) void dcn_fused_mfma(
    const float* __restrict__ x, const unsigned short* __restrict__ wpk2,
    const unsigned short* __restrict__ wopk, const float* __restrict__ b_off,
    const float* __restrict__ b_dcn, float* __restrict__ out) {
    __shared__ __align__(16) unsigned char smem[69248];
    unsigned short* win = (unsigned short*)smem;             // [8][WSEGU]
    unsigned short* omr = (unsigned short*)(smem + 55424);   // [27][256] bf16

    int tid = threadIdx.x, bid = blockIdx.x;
    int b = bid & 7;                 // batch -> XCD pinning
    int T = bid >> 3;                // tile 0..63 per image
    int y = (T >> 2) * 8;            // tile row base (8 rows)
    int x0 = (T & 3) * 32;           // tile col base
    int lane = tid & 63, wv = tid >> 6;   // wv 0..7
    int quad = lane >> 4, n16 = lane & 15;
    int n32 = lane & 31, h5 = lane >> 5;

    const float* xbf = x + (size_t)b * CH * HWSZ;

    // ---------------- Stage window from NCHW fp32 ----------------
    for (int p = tid; p < 8 * TSLOTS; p += 512) {     // 7 iters (3456/512)
        int c8 = p / TSLOTS, slot = p - c8 * TSLOTS;
        int wy = slot / TCOLS, wx = slot - wy * TCOLS;
        int iy = y - 2 + wy, ix = x0 - 2 + wx;
        bool v = (iy >= 0) & (iy < HH) & (ix >= 0) & (ix < WW);
        uint4 q = {0, 0, 0, 0};
        if (v) q = ld8g(xbf + (size_t)(c8 * 8) * HWSZ + iy * WW + ix);
        *(uint4*)&win[c8 * WSEGU + slot * 8] = q;
    }
    __syncthreads();

    // ---------------- Phase 1: offset GEMM (16x16x32, B from window) ------
    {
        int coh = wv & 1;
        int pxh = (wv >> 1) * 64;        // this wave's 64-px quarter
        f32x4 oacc[4] = {{0, 0, 0, 0}, {0, 0, 0, 0}, {0, 0, 0, 0}, {0, 0, 0, 0}};
        for (int k = 0; k < KTAPS; ++k) {
            int ky = k / 3, kx = k - ky * 3;
#pragma unroll
            for (int h = 0; h < 2; ++h) {
                short8 afrag = *(const short8*)(wopk + (size_t)((coh * 18 + k * 2 + h) * 64 + lane) * 8);
                const unsigned short* seg = win + (h * 4 + quad) * WSEGU;
#pragma unroll
                for (int pt = 0; pt < 4; ++pt) {
                    int pxp = pxh + pt * 16 + n16;
                    int prw = pxp >> 5, pcc = pxp & 31;
                    int slot = (prw + ky + 1) * TCOLS + pcc + kx + 1;
                    short8 bfrag = *(const short8*)(seg + slot * 8);
                    oacc[pt] = __builtin_amdgcn_mfma_f32_16x16x32_bf16(afrag, bfrag,
                                                                       oacc[pt], 0, 0, 0);
                }
            }
        }
#pragma unroll
        for (int pt = 0; pt < 4; ++pt) {
#pragma unroll
            for (int r = 0; r < 4; ++r) {
                int co = coh * 16 + quad * 4 + r;
                if (co < 27)
                    omr[co * 256 + pxh + pt * 16 + n16] = f2bf(oacc[pt][r] + b_off[co]);
            }
        }
    }
    __syncthreads();

    // ---------------- Phase 3: main GEMM (32x32x16), params fused ---------
    f32x16 acc[2] = {{0, 0, 0, 0, 0, 0, 0, 0, 0, 0, 0, 0, 0, 0, 0, 0},
                     {0, 0, 0, 0, 0, 0, 0, 0, 0, 0, 0, 0, 0, 0, 0, 0}};
    int pl = wv * 32 + n32;                 // this lane's px (x2 over h5)
    int ho = y + (pl >> 5), wo = x0 + (pl & 31);
    float fybase = (float)(ho - 1), fxbase = (float)(wo - 1);

#pragma unroll 3
    for (int t = 0; t < KTAPS; ++t) {
        int ky = t / 3, kx = t - ky * 3;
        // ---- bilinear params for (tap t, px pl), register-only ----
        float fy = bf2f(omr[t * 256 + pl]) + fybase + (float)ky;
        float fx = bf2f(omr[(9 + t) * 256 + pl]) + fxbase + (float)kx;
        float m = 1.f / (1.f + __expf(-bf2f(omr[(18 + t) * 256 + pl])));
        float y0f = floorf(fy), x0f = floorf(fx);
        float dy = fy - y0f, dx = fx - x0f;
        int y0 = (int)y0f, x0i = (int)x0f;
        int y1 = y0 + 1, x1 = x0i + 1;
        bool vy0 = (y0 >= 0) & (y0 < HH);
        bool vy1 = (y1 >= 0) & (y1 < HH);
        bool vx0 = (x0i >= 0) & (x0i < WW);
        bool vx1 = (x1 >= 0) & (x1 < WW);
        float w00 = (1.f - dy) * (1.f - dx) * m; if (!(vy0 && vx0)) w00 = 0.f;
        float w01 = (1.f - dy) * dx * m;         if (!(vy0 && vx1)) w01 = 0.f;
        float w10 = dy * (1.f - dx) * m;         if (!(vy1 && vx0)) w10 = 0.f;
        float w11 = dy * dx * m;                 if (!(vy1 && vx1)) w11 = 0.f;
        int yc0 = min(max(y0, 0), HH - 1), yc1 = min(max(y1, 0), HH - 1);
        int xc0 = min(max(x0i, 0), WW - 1), xc1 = min(max(x1, 0), WW - 1);
        int uy = y0 - (y - 2), ux = x0i - (x0 - 2);
        bool inw = ((unsigned)uy <= 10u) & ((unsigned)ux <= 34u);
        unsigned int iu;
        if (inw) iu = (unsigned)(uy * TCOLS + ux);
        else     iu = 0x80000000u | ((unsigned)yc0 << 21) | ((unsigned)xc0 << 14)
                                  | ((unsigned)yc1 << 7)  | (unsigned)xc1;

        // ---- 4 K-steps of 16 ch; lane's 8 ch = segment 2s+h5 ----
#pragma unroll
        for (int s = 0; s < 4; ++s) {
            int g = 2 * s + h5;
            uint4 qa, qb, qc, qd;
            if (__builtin_expect(!(iu & 0x80000000u), 1)) {
                const unsigned short* base = win + g * WSEGU + iu * 8;
                qa = *(const uint4*)(base);
                qb = *(const uint4*)(base + 8);
                qc = *(const uint4*)(base + TCOLS * 8);
                qd = *(const uint4*)(base + TCOLS * 8 + 8);
            } else {
                int zy0 = (int)((iu >> 21) & 0x7f), zx0 = (int)((iu >> 14) & 0x7f);
                int zy1 = (int)((iu >> 7) & 0x7f),  zx1 = (int)(iu & 0x7f);
                const float* pc0 = xbf + (size_t)(g * 8) * HWSZ;
                qa = ld8g(pc0 + zy0 * WW + zx0); qb = ld8g(pc0 + zy0 * WW + zx1);
                qc = ld8g(pc0 + zy1 * WW + zx0); qd = ld8g(pc0 + zy1 * WW + zx1);
            }
            union { uint4 u; short8 sh; } cv;
            cv.u.x = bilin2(qa.x, qb.x, qc.x, qd.x, w00, w01, w10, w11);
            cv.u.y = bilin2(qa.y, qb.y, qc.y, qd.y, w00, w01, w10, w11);
            cv.u.z = bilin2(qa.z, qb.z, qc.z, qd.z, w00, w01, w10, w11);
            cv.u.w = bilin2(qa.w, qb.w, qc.w, qd.w, w00, w01, w10, w11);
            short8 bfrag = cv.sh;

            short8 af0 = *(const short8*)(wpk2 + (size_t)(((0 * 9 + t) * 4 + s) * 64 + lane) * 8);
            acc[0] = __builtin_amdgcn_mfma_f32_32x32x16_bf16(af0, bfrag, acc[0], 0, 0, 0);
            short8 af1 = *(const short8*)(wpk2 + (size_t)(((1 * 9 + t) * 4 + s) * 64 + lane) * 8);
            acc[1] = __builtin_amdgcn_mfma_f32_32x32x16_bf16(af1, bfrag, acc[1], 0, 0, 0);
        }
    }

    // Epilogue: 32x32 C/D: col(px) = lane&31; row = (r&3)+8*(r>>2)+4*h5
    float* ob = out + (size_t)b * COUT * HWSZ;
    int gidx = (y + (pl >> 5)) * WW + x0 + (pl & 31);
#pragma unroll
    for (int cot = 0; cot < 2; ++cot) {
#pragma unroll
        for (int r = 0; r < 16; ++r) {
            int co = cot * 32 + (r & 3) + 8 * (r >> 2) + 4 * h5;
            ob[(size_t)co * HWSZ + gidx] = acc[cot][r] + b_dcn[co];
        }
    }
}

// ---------------------------------------------------------------------------
extern "C" void kernel_launch(void* const* d_in, const int* in_sizes, int n_in,
                              void* d_out, int out_size, void* d_ws, size_t ws_size,
                              hipStream_t stream) {
    const float* x     = (const float*)d_in[0];
    const float* w_off = (const float*)d_in[1];
    const float* b_off = (const float*)d_in[2];
    const float* w_dcn = (const float*)d_in[3];
    const float* b_dcn = (const float*)d_in[4];
    float* out = (float*)d_out;

    // ws layout: wpk2 (36864 ush) | wopk (18432 ush)
    unsigned short* wpk2 = (unsigned short*)d_ws;
    unsigned short* wopk = wpk2 + 36864;

    hipLaunchKernelGGL(prep_w_kernel, dim3(216), dim3(256), 0, stream,
                       w_dcn, w_off, wpk2, wopk);
    hipLaunchKernelGGL(dcn_fused_mfma, dim3(NBLK), dim3(512),
                       0, stream, x, wpk2, wopk, b_off, b_dcn, out);
}